// Round 10
// baseline (127.352 us; speedup 1.0000x reference)
//
#include <hip/hip_runtime.h>
#include <hip/hip_bf16.h>

typedef __attribute__((ext_vector_type(8))) short short8_t;
typedef __attribute__((ext_vector_type(4))) float f32x4;

#define NB 2
#define CC 64
#define RCC 8
#define NN 9216
#define QT64TILES 144       // 64-query tiles per batch
#define NQ32 288            // 32-query tiles per batch
#define PPART_B 4224        // bytes: [32q][64ch] bf16 O (4096) + 32 f32 rowsums (128)

static __device__ __forceinline__ unsigned short f2bf(float f) {
    unsigned int u = __builtin_bit_cast(unsigned int, f);
    u += 0x7fffu + ((u >> 16) & 1u);
    return (unsigned short)(u >> 16);
}
static __device__ __forceinline__ unsigned int cvt_pk_bf16(float lo, float hi) {
    unsigned int r;
    asm("v_cvt_pk_bf16_f32 %0, %1, %2" : "=v"(r) : "v"(lo), "v"(hi));
    return r;
}

// ---------------- projection kernel (VERBATIM from passing R6) ----------------
// grid = (B*N/256, 2), 256 threads. y=0: q + v[0:32); y=1: k + v[32:64).
// q scale folds 1/sqrt(N), log2(e), and 1/4 (replicate-x4 MFMA trick).
// V stored kslot-PERMUTED within each aligned 32-key group:
//   pos 8g+s (s=0..3) holds key 4g+s; pos 8g+4+s holds key 16+4g+s
__global__ __launch_bounds__(256) void proj_kernel(
    const float* __restrict__ x,
    const float* __restrict__ wq, const float* __restrict__ bq,
    const float* __restrict__ wk, const float* __restrict__ bk,
    const float* __restrict__ wv, const float* __restrict__ bv,
    unsigned short* __restrict__ qbf,   // [B][N][8] bf16
    unsigned short* __restrict__ kbf,   // [B][N][8] bf16
    unsigned short* __restrict__ vbf)   // [B][C][N] bf16, permuted
{
    const int grp = blockIdx.y;
    __shared__ float sw[40 * CC];
    __shared__ float sb[40];
    const int t = threadIdx.x;

    const float* w8 = grp ? wk : wq;
    const float* b8 = grp ? bk : bq;
    for (int i = t; i < 8 * CC; i += 256) sw[i] = w8[i];
    for (int i = t; i < 32 * CC; i += 256) sw[8 * CC + i] = wv[grp * 32 * CC + i];
    if (t < 8) sb[t] = b8[t];
    else if (t < 40) sb[t] = bv[grp * 32 + (t - 8)];
    __syncthreads();

    const int gid = blockIdx.x * 256 + t;    // 0 .. B*N-1 exact
    const int b = gid / NN, n = gid % NN;
    const float* xp = x + (size_t)b * CC * NN + n;
    float xv[CC];
    #pragma unroll
    for (int c = 0; c < CC; ++c) xv[c] = xp[(size_t)c * NN];

    const float scale = grp ? 1.0f : 0.0037570183356483423f; // log2e/(96*4)
    unsigned short* dst = grp ? kbf : qbf;
    union { unsigned short u[8]; uint4 q4; } pk;
    #pragma unroll
    for (int r = 0; r < RCC; ++r) {
        const float4* wr = (const float4*)&sw[r * CC];
        float a = sb[r];
        #pragma unroll
        for (int c4 = 0; c4 < CC / 4; ++c4) {
            float4 wd = wr[c4];
            a += wd.x * xv[4*c4] + wd.y * xv[4*c4+1] + wd.z * xv[4*c4+2] + wd.w * xv[4*c4+3];
        }
        pk.u[r] = f2bf(a * scale);
    }
    *(uint4*)(dst + (size_t)gid * RCC) = pk.q4;

    // kslot-permuted V position
    const int n32 = n & 31;
    const int np = (n & ~31) | ((n32 & 12) << 1) | (n32 & 3) | ((n32 >> 2) & 4);
    for (int o = 0; o < 32; ++o) {
        const float4* wr = (const float4*)&sw[(8 + o) * CC];
        float a = sb[8 + o];
        #pragma unroll
        for (int c4 = 0; c4 < CC / 4; ++c4) {
            float4 wd = wr[c4];
            a += wd.x * xv[4*c4] + wd.y * xv[4*c4+1] + wd.z * xv[4*c4+2] + wd.w * xv[4*c4+3];
        }
        vbf[((size_t)b * CC + grp * 32 + o) * NN + np] = f2bf(a);
    }
}

// ---------------- attention kernel ----------------
// grid = NB*QT64TILES*KSPL blocks (ks fastest), 128 threads = 2 waves.
// Each WAVE independently owns 32 queries x ALL 64 channels x the block's
// key-slice (KPB = NN/KSPL keys). No LDS, no barriers, no cross-wave reduce.
// Both waves read identical K/V addresses -> L1 hits. Arithmetic identical
// to the proven R6 path (replicate-x4 QK, kslot-permuted V, exp2, cvt_pk).
#define COMPUTE(K0, K1, V0, V1, V2, V3) do {                                 \
    __builtin_amdgcn_s_setprio(1);                                           \
    _Pragma("unroll")                                                        \
    for (int j = 0; j < 2; ++j) {                                            \
        f32x4 s0 = __builtin_amdgcn_mfma_f32_16x16x32_bf16(K0, qf[j], zero4, 0, 0, 0); \
        f32x4 s1 = __builtin_amdgcn_mfma_f32_16x16x32_bf16(K1, qf[j], zero4, 0, 0, 0); \
        float p0 = __builtin_amdgcn_exp2f(s0[0]);                            \
        float p1 = __builtin_amdgcn_exp2f(s0[1]);                            \
        float p2 = __builtin_amdgcn_exp2f(s0[2]);                            \
        float p3 = __builtin_amdgcn_exp2f(s0[3]);                            \
        float p4 = __builtin_amdgcn_exp2f(s1[0]);                            \
        float p5 = __builtin_amdgcn_exp2f(s1[1]);                            \
        float p6 = __builtin_amdgcn_exp2f(s1[2]);                            \
        float p7 = __builtin_amdgcn_exp2f(s1[3]);                            \
        rs[j] += ((p0 + p1) + (p2 + p3)) + ((p4 + p5) + (p6 + p7));          \
        union { unsigned int u[4]; short8_t v; } pw;                         \
        pw.u[0] = cvt_pk_bf16(p0, p1);                                       \
        pw.u[1] = cvt_pk_bf16(p2, p3);                                       \
        pw.u[2] = cvt_pk_bf16(p4, p5);                                       \
        pw.u[3] = cvt_pk_bf16(p6, p7);                                       \
        const short8_t pb = pw.v;                                            \
        acc[0][j] = __builtin_amdgcn_mfma_f32_16x16x32_bf16(V0, pb, acc[0][j], 0, 0, 0); \
        acc[1][j] = __builtin_amdgcn_mfma_f32_16x16x32_bf16(V1, pb, acc[1][j], 0, 0, 0); \
        acc[2][j] = __builtin_amdgcn_mfma_f32_16x16x32_bf16(V2, pb, acc[2][j], 0, 0, 0); \
        acc[3][j] = __builtin_amdgcn_mfma_f32_16x16x32_bf16(V3, pb, acc[3][j], 0, 0, 0); \
    }                                                                        \
    __builtin_amdgcn_s_setprio(0);                                           \
} while (0)

template<int KSPL>
__global__ __launch_bounds__(128) void attn_kernel(
    const unsigned short* __restrict__ qbf,
    const unsigned short* __restrict__ kbf,
    const unsigned short* __restrict__ vbf,
    char* __restrict__ pbuf)
{
    constexpr int KPB = NN / KSPL;       // keys per block (= per wave)
    constexpr int NCH = KPB / 32;        // 32-key chunks; even for KSPL in {1,2,4,8}
    static_assert(NCH % 2 == 0, "even NCH");

    const int tid = threadIdx.x;
    const int w = tid >> 6, l = tid & 63, g = l >> 4, li = l & 15;

    const int bid = blockIdx.x;
    const int ks   = bid % KSPL;         // fastest -> XCD L2 locality
    const int rest = bid / KSPL;
    const int b    = rest & 1;
    const int qt64 = rest >> 1;          // 0..143
    const int qbase = qt64 * 64 + w * 32;
    const int q32   = qt64 * 2 + w;      // 0..287

    const unsigned short* qb = qbf + (size_t)b * NN * RCC;
    const unsigned short* kp = kbf + (size_t)b * NN * RCC;
    const unsigned short* vb = vbf + (size_t)b * CC * NN;
    const unsigned short* vr0 = vb + (size_t)li * NN;
    const unsigned short* vr1 = vb + (size_t)(16 + li) * NN;
    const unsigned short* vr2 = vb + (size_t)(32 + li) * NN;
    const unsigned short* vr3 = vb + (size_t)(48 + li) * NN;
    const int vo = 8 * g;

    short8_t qf[2];
    #pragma unroll
    for (int j = 0; j < 2; ++j)
        qf[j] = *(const short8_t*)(qb + (size_t)(qbase + 16 * j + li) * RCC);

    const f32x4 zero4 = {0.f, 0.f, 0.f, 0.f};
    f32x4 acc[4][2];    // [f = ch/16][j = q/16]
    #pragma unroll
    for (int f = 0; f < 4; ++f)
        #pragma unroll
        for (int j = 0; j < 2; ++j) acc[f][j] = zero4;
    float rs[2] = {0.f, 0.f};

    int k0 = ks * KPB;
    short8_t kA0 = *(const short8_t*)(kp + (size_t)(k0 + li) * RCC);
    short8_t kA1 = *(const short8_t*)(kp + (size_t)(k0 + 16 + li) * RCC);
    short8_t kB0, kB1, v0, v1, v2, v3, u0, u1, u2, u3;

    for (int c = 0; c < NCH; c += 2) {
        // V(c) issued early (consumed after S'+exp chain); K(c+1) prefetch
        v0 = *(const short8_t*)(vr0 + k0 + vo);
        v1 = *(const short8_t*)(vr1 + k0 + vo);
        v2 = *(const short8_t*)(vr2 + k0 + vo);
        v3 = *(const short8_t*)(vr3 + k0 + vo);
        kB0 = *(const short8_t*)(kp + (size_t)(k0 + 32 + li) * RCC);
        kB1 = *(const short8_t*)(kp + (size_t)(k0 + 48 + li) * RCC);
        COMPUTE(kA0, kA1, v0, v1, v2, v3);
        u0 = *(const short8_t*)(vr0 + k0 + 32 + vo);
        u1 = *(const short8_t*)(vr1 + k0 + 32 + vo);
        u2 = *(const short8_t*)(vr2 + k0 + 32 + vo);
        u3 = *(const short8_t*)(vr3 + k0 + 32 + vo);
        if (c + 2 < NCH) {
            kA0 = *(const short8_t*)(kp + (size_t)(k0 + 64 + li) * RCC);
            kA1 = *(const short8_t*)(kp + (size_t)(k0 + 80 + li) * RCC);
        }
        COMPUTE(kB0, kB1, u0, u1, u2, u3);
        k0 += 64;
    }

    // rowsum reduce across lane-groups: every lane ends with full sum for q=16j+li
    #pragma unroll
    for (int j = 0; j < 2; ++j) {
        rs[j] += __shfl_xor(rs[j], 16, 64);
        rs[j] += __shfl_xor(rs[j], 32, 64);
    }

    // ---- write partial: [32q][64ch] bf16 (8B stores) + 32 f32 rowsums ----
    const size_t p = ((size_t)(b * NQ32 + q32) * KSPL + ks);
    unsigned short* po = (unsigned short*)(pbuf + p * PPART_B);
    #pragma unroll
    for (int j = 0; j < 2; ++j) {
        #pragma unroll
        for (int f = 0; f < 4; ++f) {
            uint2 d;
            d.x = cvt_pk_bf16(acc[f][j][0], acc[f][j][1]);
            d.y = cvt_pk_bf16(acc[f][j][2], acc[f][j][3]);
            *(uint2*)(po + (16 * j + li) * CC + 16 * f + 4 * g) = d;
        }
    }
    if (g == 0) {
        float* prs = (float*)(pbuf + p * PPART_B + 4096);
        prs[li]      = rs[0];
        prs[16 + li] = rs[1];
    }
}

// ---------------- combine kernel ----------------
// grid = NB*NQ32 blocks, 256 threads. Block (b, q32): sum KSPL partials,
// normalize, residual, write. Partial reads are uint4-coalesced.
template<int KSPL>
__global__ __launch_bounds__(256) void combine_kernel(
    const char* __restrict__ pbuf,
    const float* __restrict__ x,
    const float* __restrict__ gamma,
    float* __restrict__ out)
{
    const int bid = blockIdx.x;          // b + 2*... decode: b = bid&1, q32 = bid>>1
    const int b = bid & 1, q32 = bid >> 1;
    const char* pc = pbuf + (size_t)(b * NQ32 + q32) * KSPL * PPART_B;
    const int t = threadIdx.x;
    const int q = t >> 3;                // 0..31
    const int c8 = (t & 7) * 8;          // channel base 0..56

    float den = 0.f;
    #pragma unroll
    for (int s = 0; s < KSPL; ++s)
        den += *(const float*)(pc + (size_t)s * PPART_B + 4096 + 4 * q);
    const float inv = 1.0f / den;
    const float gm = gamma[0];

    float o[8];
    #pragma unroll
    for (int i = 0; i < 8; ++i) o[i] = 0.f;
    #pragma unroll
    for (int s = 0; s < KSPL; ++s) {
        uint4 uu = *(const uint4*)(pc + (size_t)s * PPART_B + (size_t)(q * CC + c8) * 2);
        o[0] += __builtin_bit_cast(float, uu.x << 16);
        o[1] += __builtin_bit_cast(float, uu.x & 0xffff0000u);
        o[2] += __builtin_bit_cast(float, uu.y << 16);
        o[3] += __builtin_bit_cast(float, uu.y & 0xffff0000u);
        o[4] += __builtin_bit_cast(float, uu.z << 16);
        o[5] += __builtin_bit_cast(float, uu.z & 0xffff0000u);
        o[6] += __builtin_bit_cast(float, uu.w << 16);
        o[7] += __builtin_bit_cast(float, uu.w & 0xffff0000u);
    }
    #pragma unroll
    for (int i = 0; i < 8; ++i) {
        const int ch = c8 + i;
        const size_t i0 = ((size_t)b * CC + ch) * NN + (size_t)q32 * 32 + q;
        out[i0] = x[i0] + gm * o[i] * inv;
    }
}

extern "C" void kernel_launch(void* const* d_in, const int* in_sizes, int n_in,
                              void* d_out, int out_size, void* d_ws, size_t ws_size,
                              hipStream_t stream) {
    const float* x     = (const float*)d_in[0];
    const float* wq    = (const float*)d_in[1];
    const float* bq    = (const float*)d_in[2];
    const float* wk    = (const float*)d_in[3];
    const float* bk    = (const float*)d_in[4];
    const float* wv    = (const float*)d_in[5];
    const float* bv    = (const float*)d_in[6];
    const float* gamma = (const float*)d_in[7];
    float* out = (float*)d_out;

    unsigned short* qbf = (unsigned short*)d_ws;
    unsigned short* kbf = qbf + (size_t)NB * NN * RCC;
    unsigned short* vbf = kbf + (size_t)NB * NN * RCC;
    size_t bufbytes = ((size_t)2 * NB * NN * RCC + (size_t)NB * CC * NN) * sizeof(unsigned short);
    size_t poff = (bufbytes + 255) & ~(size_t)255;
    char* pbuf = (char*)d_ws + poff;
    size_t avail = ws_size > poff ? ws_size - poff : 0;

    proj_kernel<<<dim3((NB * NN) / 256, 2), 256, 0, stream>>>(
        x, wq, bq, wk, bk, wv, bv, qbf, kbf, vbf);

    auto fits = [&](int kspl) {
        return avail >= (size_t)NB * NQ32 * kspl * PPART_B;
    };

    if (fits(8)) {
        attn_kernel<8><<<NB * QT64TILES * 8, 128, 0, stream>>>(qbf, kbf, vbf, pbuf);
        combine_kernel<8><<<NB * NQ32, 256, 0, stream>>>(pbuf, x, gamma, out);
    } else if (fits(4)) {
        attn_kernel<4><<<NB * QT64TILES * 4, 128, 0, stream>>>(qbf, kbf, vbf, pbuf);
        combine_kernel<4><<<NB * NQ32, 256, 0, stream>>>(pbuf, x, gamma, out);
    } else if (fits(2)) {
        attn_kernel<2><<<NB * QT64TILES * 2, 128, 0, stream>>>(qbf, kbf, vbf, pbuf);
        combine_kernel<2><<<NB * NQ32, 256, 0, stream>>>(pbuf, x, gamma, out);
    } else {
        attn_kernel<1><<<NB * QT64TILES * 1, 128, 0, stream>>>(qbf, kbf, vbf, pbuf);
        combine_kernel<1><<<NB * NQ32, 256, 0, stream>>>(pbuf, x, gamma, out);
    }
}

// Round 11
// 95.434 us; speedup vs baseline: 1.3345x; 1.3345x over previous
//
#include <hip/hip_runtime.h>
#include <hip/hip_bf16.h>

typedef __attribute__((ext_vector_type(8))) short short8_t;
typedef __attribute__((ext_vector_type(4))) float f32x4;

#define NB 2
#define CC 64
#define RCC 8
#define NN 9216
#define QT64TILES 144       // 64-query tiles per batch
#define PPART_B 8448        // bytes: [64q][64ch] bf16 O (8192) + 64 f32 rowsums (256)

static __device__ __forceinline__ unsigned short f2bf(float f) {
    unsigned int u = __builtin_bit_cast(unsigned int, f);
    u += 0x7fffu + ((u >> 16) & 1u);
    return (unsigned short)(u >> 16);
}
static __device__ __forceinline__ unsigned int cvt_pk_bf16(float lo, float hi) {
    unsigned int r;
    asm("v_cvt_pk_bf16_f32 %0, %1, %2" : "=v"(r) : "v"(lo), "v"(hi));
    return r;
}

// ---------------- projection kernel (VERBATIM from passing R6/R10) ----------------
// grid = (B*N/256, 2), 256 threads. y=0: q + v[0:32); y=1: k + v[32:64).
// q scale folds 1/sqrt(N), log2(e), and 1/4 (replicate-x4 MFMA trick).
// V stored kslot-PERMUTED within each aligned 32-key group:
//   pos 8g+s (s=0..3) holds key 4g+s; pos 8g+4+s holds key 16+4g+s
__global__ __launch_bounds__(256) void proj_kernel(
    const float* __restrict__ x,
    const float* __restrict__ wq, const float* __restrict__ bq,
    const float* __restrict__ wk, const float* __restrict__ bk,
    const float* __restrict__ wv, const float* __restrict__ bv,
    unsigned short* __restrict__ qbf,   // [B][N][8] bf16
    unsigned short* __restrict__ kbf,   // [B][N][8] bf16
    unsigned short* __restrict__ vbf)   // [B][C][N] bf16, permuted
{
    const int grp = blockIdx.y;
    __shared__ float sw[40 * CC];
    __shared__ float sb[40];
    const int t = threadIdx.x;

    const float* w8 = grp ? wk : wq;
    const float* b8 = grp ? bk : bq;
    for (int i = t; i < 8 * CC; i += 256) sw[i] = w8[i];
    for (int i = t; i < 32 * CC; i += 256) sw[8 * CC + i] = wv[grp * 32 * CC + i];
    if (t < 8) sb[t] = b8[t];
    else if (t < 40) sb[t] = bv[grp * 32 + (t - 8)];
    __syncthreads();

    const int gid = blockIdx.x * 256 + t;    // 0 .. B*N-1 exact
    const int b = gid / NN, n = gid % NN;
    const float* xp = x + (size_t)b * CC * NN + n;
    float xv[CC];
    #pragma unroll
    for (int c = 0; c < CC; ++c) xv[c] = xp[(size_t)c * NN];

    const float scale = grp ? 1.0f : 0.0037570183356483423f; // log2e/(96*4)
    unsigned short* dst = grp ? kbf : qbf;
    union { unsigned short u[8]; uint4 q4; } pk;
    #pragma unroll
    for (int r = 0; r < RCC; ++r) {
        const float4* wr = (const float4*)&sw[r * CC];
        float a = sb[r];
        #pragma unroll
        for (int c4 = 0; c4 < CC / 4; ++c4) {
            float4 wd = wr[c4];
            a += wd.x * xv[4*c4] + wd.y * xv[4*c4+1] + wd.z * xv[4*c4+2] + wd.w * xv[4*c4+3];
        }
        pk.u[r] = f2bf(a * scale);
    }
    *(uint4*)(dst + (size_t)gid * RCC) = pk.q4;

    // kslot-permuted V position
    const int n32 = n & 31;
    const int np = (n & ~31) | ((n32 & 12) << 1) | (n32 & 3) | ((n32 >> 2) & 4);
    for (int o = 0; o < 32; ++o) {
        const float4* wr = (const float4*)&sw[(8 + o) * CC];
        float a = sb[8 + o];
        #pragma unroll
        for (int c4 = 0; c4 < CC / 4; ++c4) {
            float4 wd = wr[c4];
            a += wd.x * xv[4*c4] + wd.y * xv[4*c4+1] + wd.z * xv[4*c4+2] + wd.w * xv[4*c4+3];
        }
        vbf[((size_t)b * CC + grp * 32 + o) * NN + np] = f2bf(a);
    }
}

// ---------------- attention kernel ----------------
// grid = NB*QT64TILES*KSPL blocks (ks fastest -> XCD L2 locality), 128 thr
// = 2 waves. Each WAVE independently: 64 queries x ALL 64 channels x its
// half of the block's key-slice (KPW = NN/KSPL/2 keys, NCH = KPW/32 even).
// No LDS, no barriers, no cross-wave reduce. K double-buffered, V issued
// at chunk start (consumed after the QK+exp chain). Proven R6 arithmetic.
#define COMPUTE(K0, K1, V0, V1, V2, V3) do {                                 \
    __builtin_amdgcn_s_setprio(1);                                           \
    _Pragma("unroll")                                                        \
    for (int j = 0; j < 4; ++j) {                                            \
        f32x4 s0 = __builtin_amdgcn_mfma_f32_16x16x32_bf16(K0, qf[j], zero4, 0, 0, 0); \
        f32x4 s1 = __builtin_amdgcn_mfma_f32_16x16x32_bf16(K1, qf[j], zero4, 0, 0, 0); \
        float p0 = __builtin_amdgcn_exp2f(s0[0]);                            \
        float p1 = __builtin_amdgcn_exp2f(s0[1]);                            \
        float p2 = __builtin_amdgcn_exp2f(s0[2]);                            \
        float p3 = __builtin_amdgcn_exp2f(s0[3]);                            \
        float p4 = __builtin_amdgcn_exp2f(s1[0]);                            \
        float p5 = __builtin_amdgcn_exp2f(s1[1]);                            \
        float p6 = __builtin_amdgcn_exp2f(s1[2]);                            \
        float p7 = __builtin_amdgcn_exp2f(s1[3]);                            \
        rs[j] += ((p0 + p1) + (p2 + p3)) + ((p4 + p5) + (p6 + p7));          \
        union { unsigned int u[4]; short8_t v; } pw;                         \
        pw.u[0] = cvt_pk_bf16(p0, p1);                                       \
        pw.u[1] = cvt_pk_bf16(p2, p3);                                       \
        pw.u[2] = cvt_pk_bf16(p4, p5);                                       \
        pw.u[3] = cvt_pk_bf16(p6, p7);                                       \
        const short8_t pb = pw.v;                                            \
        acc[0][j] = __builtin_amdgcn_mfma_f32_16x16x32_bf16(V0, pb, acc[0][j], 0, 0, 0); \
        acc[1][j] = __builtin_amdgcn_mfma_f32_16x16x32_bf16(V1, pb, acc[1][j], 0, 0, 0); \
        acc[2][j] = __builtin_amdgcn_mfma_f32_16x16x32_bf16(V2, pb, acc[2][j], 0, 0, 0); \
        acc[3][j] = __builtin_amdgcn_mfma_f32_16x16x32_bf16(V3, pb, acc[3][j], 0, 0, 0); \
    }                                                                        \
    __builtin_amdgcn_s_setprio(0);                                           \
} while (0)

template<int KSPL>
__global__ __launch_bounds__(128) void attn_kernel(
    const unsigned short* __restrict__ qbf,
    const unsigned short* __restrict__ kbf,
    const unsigned short* __restrict__ vbf,
    char* __restrict__ pbuf)
{
    constexpr int KPB = NN / KSPL;       // keys per block
    constexpr int KPW = KPB / 2;         // keys per wave
    constexpr int NCH = KPW / 32;        // 32-key chunks per wave
    static_assert(NCH % 2 == 0, "even NCH");

    const int tid = threadIdx.x;
    const int w = tid >> 6, l = tid & 63, g = l >> 4, li = l & 15;

    const int bid = blockIdx.x;
    const int ks   = bid % KSPL;         // fastest -> XCD L2 locality
    const int rest = bid / KSPL;
    const int b    = rest & 1;
    const int qt64 = rest >> 1;          // 0..143
    const int qbase = qt64 * 64;
    const int key_base = ks * KPB + w * KPW;

    const unsigned short* qb = qbf + (size_t)b * NN * RCC;
    const unsigned short* kp = kbf + (size_t)b * NN * RCC;
    const unsigned short* vb = vbf + (size_t)b * CC * NN;
    const unsigned short* vr0 = vb + (size_t)li * NN;
    const unsigned short* vr1 = vb + (size_t)(16 + li) * NN;
    const unsigned short* vr2 = vb + (size_t)(32 + li) * NN;
    const unsigned short* vr3 = vb + (size_t)(48 + li) * NN;
    const int vo = 8 * g;

    short8_t qf[4];
    #pragma unroll
    for (int j = 0; j < 4; ++j)
        qf[j] = *(const short8_t*)(qb + (size_t)(qbase + 16 * j + li) * RCC);

    const f32x4 zero4 = {0.f, 0.f, 0.f, 0.f};
    f32x4 acc[4][4];    // [f = ch/16][j = q/16]
    #pragma unroll
    for (int f = 0; f < 4; ++f)
        #pragma unroll
        for (int j = 0; j < 4; ++j) acc[f][j] = zero4;
    float rs[4] = {0.f, 0.f, 0.f, 0.f};

    int k0 = key_base;
    short8_t kA0 = *(const short8_t*)(kp + (size_t)(k0 + li) * RCC);
    short8_t kA1 = *(const short8_t*)(kp + (size_t)(k0 + 16 + li) * RCC);
    short8_t kB0, kB1, v0, v1, v2, v3;

    for (int c = 0; c < NCH; c += 2) {
        // V(c) issued early; K(c+1) prefetch; then compute chunk c
        v0 = *(const short8_t*)(vr0 + k0 + vo);
        v1 = *(const short8_t*)(vr1 + k0 + vo);
        v2 = *(const short8_t*)(vr2 + k0 + vo);
        v3 = *(const short8_t*)(vr3 + k0 + vo);
        kB0 = *(const short8_t*)(kp + (size_t)(k0 + 32 + li) * RCC);
        kB1 = *(const short8_t*)(kp + (size_t)(k0 + 48 + li) * RCC);
        COMPUTE(kA0, kA1, v0, v1, v2, v3);
        // V(c+1) issued early; K(c+2) prefetch; compute chunk c+1
        v0 = *(const short8_t*)(vr0 + k0 + 32 + vo);
        v1 = *(const short8_t*)(vr1 + k0 + 32 + vo);
        v2 = *(const short8_t*)(vr2 + k0 + 32 + vo);
        v3 = *(const short8_t*)(vr3 + k0 + 32 + vo);
        if (c + 2 < NCH) {
            kA0 = *(const short8_t*)(kp + (size_t)(k0 + 64 + li) * RCC);
            kA1 = *(const short8_t*)(kp + (size_t)(k0 + 80 + li) * RCC);
        }
        COMPUTE(kB0, kB1, v0, v1, v2, v3);
        k0 += 64;
    }

    // rowsum reduce across lane-groups: every lane ends with full sum for q=16j+li
    #pragma unroll
    for (int j = 0; j < 4; ++j) {
        rs[j] += __shfl_xor(rs[j], 16, 64);
        rs[j] += __shfl_xor(rs[j], 32, 64);
    }

    // ---- write partial: [64q][64ch] bf16 (8B stores) + 64 f32 rowsums ----
    const size_t p = ((size_t)(b * QT64TILES + qt64) * KSPL + ks) * 2 + w;
    unsigned short* po = (unsigned short*)(pbuf + p * PPART_B);
    #pragma unroll
    for (int j = 0; j < 4; ++j) {
        #pragma unroll
        for (int f = 0; f < 4; ++f) {
            uint2 d;
            d.x = cvt_pk_bf16(acc[f][j][0], acc[f][j][1]);
            d.y = cvt_pk_bf16(acc[f][j][2], acc[f][j][3]);
            *(uint2*)(po + (16 * j + li) * CC + 16 * f + 4 * g) = d;
        }
    }
    if (g == 0) {
        float* prs = (float*)(pbuf + p * PPART_B + 8192);
        #pragma unroll
        for (int j = 0; j < 4; ++j) prs[16 * j + li] = rs[j];
    }
}

// ---------------- combine kernel ----------------
// grid = NB*QT64TILES blocks, 256 threads. Block (b, qt64): sum 2*KSPL
// partials ([64q][64ch] bf16 + rowsums), normalize, residual, write.
template<int KSPL>
__global__ __launch_bounds__(256) void combine_kernel(
    const char* __restrict__ pbuf,
    const float* __restrict__ x,
    const float* __restrict__ gamma,
    float* __restrict__ out)
{
    constexpr int SPL = 2 * KSPL;
    const int bid = blockIdx.x;          // b*QT64TILES + qt64
    const int b = bid / QT64TILES, qt64 = bid % QT64TILES;
    const char* pc = pbuf + (size_t)bid * SPL * PPART_B;
    const int t = threadIdx.x;

    __shared__ float sden[64];
    if (t < 64) {
        float d = 0.f;
        #pragma unroll
        for (int s = 0; s < SPL; ++s)
            d += *(const float*)(pc + (size_t)s * PPART_B + 8192 + 4 * t);
        sden[t] = 1.0f / d;
    }
    __syncthreads();
    const float gm = gamma[0];

    const int q0 = t >> 3;               // 0..31 (also handle q0+32)
    const int c8 = (t & 7) * 8;          // channel base
    #pragma unroll
    for (int half = 0; half < 2; ++half) {
        const int q = q0 + 32 * half;
        float o[8];
        #pragma unroll
        for (int i = 0; i < 8; ++i) o[i] = 0.f;
        #pragma unroll
        for (int s = 0; s < SPL; ++s) {
            uint4 uu = *(const uint4*)(pc + (size_t)s * PPART_B + (size_t)(q * CC + c8) * 2);
            o[0] += __builtin_bit_cast(float, uu.x << 16);
            o[1] += __builtin_bit_cast(float, uu.x & 0xffff0000u);
            o[2] += __builtin_bit_cast(float, uu.y << 16);
            o[3] += __builtin_bit_cast(float, uu.y & 0xffff0000u);
            o[4] += __builtin_bit_cast(float, uu.z << 16);
            o[5] += __builtin_bit_cast(float, uu.z & 0xffff0000u);
            o[6] += __builtin_bit_cast(float, uu.w << 16);
            o[7] += __builtin_bit_cast(float, uu.w & 0xffff0000u);
        }
        const float inv = sden[q];
        #pragma unroll
        for (int i = 0; i < 8; ++i) {
            const int ch = c8 + i;
            const size_t i0 = ((size_t)b * CC + ch) * NN + (size_t)qt64 * 64 + q;
            out[i0] = x[i0] + gm * o[i] * inv;
        }
    }
}

extern "C" void kernel_launch(void* const* d_in, const int* in_sizes, int n_in,
                              void* d_out, int out_size, void* d_ws, size_t ws_size,
                              hipStream_t stream) {
    const float* x     = (const float*)d_in[0];
    const float* wq    = (const float*)d_in[1];
    const float* bq    = (const float*)d_in[2];
    const float* wk    = (const float*)d_in[3];
    const float* bk    = (const float*)d_in[4];
    const float* wv    = (const float*)d_in[5];
    const float* bv    = (const float*)d_in[6];
    const float* gamma = (const float*)d_in[7];
    float* out = (float*)d_out;

    unsigned short* qbf = (unsigned short*)d_ws;
    unsigned short* kbf = qbf + (size_t)NB * NN * RCC;
    unsigned short* vbf = kbf + (size_t)NB * NN * RCC;
    size_t bufbytes = ((size_t)2 * NB * NN * RCC + (size_t)NB * CC * NN) * sizeof(unsigned short);
    size_t poff = (bufbytes + 255) & ~(size_t)255;
    char* pbuf = (char*)d_ws + poff;
    size_t avail = ws_size > poff ? ws_size - poff : 0;

    proj_kernel<<<dim3((NB * NN) / 256, 2), 256, 0, stream>>>(
        x, wq, bq, wk, bk, wv, bv, qbf, kbf, vbf);

    auto fits = [&](int kspl) {
        return avail >= (size_t)NB * QT64TILES * kspl * 2 * PPART_B;
    };

    if (fits(8)) {
        attn_kernel<8><<<NB * QT64TILES * 8, 128, 0, stream>>>(qbf, kbf, vbf, pbuf);
        combine_kernel<8><<<NB * QT64TILES, 256, 0, stream>>>(pbuf, x, gamma, out);
    } else if (fits(4)) {
        attn_kernel<4><<<NB * QT64TILES * 4, 128, 0, stream>>>(qbf, kbf, vbf, pbuf);
        combine_kernel<4><<<NB * QT64TILES, 256, 0, stream>>>(pbuf, x, gamma, out);
    } else if (fits(2)) {
        attn_kernel<2><<<NB * QT64TILES * 2, 128, 0, stream>>>(qbf, kbf, vbf, pbuf);
        combine_kernel<2><<<NB * QT64TILES, 256, 0, stream>>>(pbuf, x, gamma, out);
    } else {
        attn_kernel<1><<<NB * QT64TILES * 1, 128, 0, stream>>>(qbf, kbf, vbf, pbuf);
        combine_kernel<1><<<NB * QT64TILES, 256, 0, stream>>>(pbuf, x, gamma, out);
    }
}